// Round 6
// baseline (1572.284 us; speedup 1.0000x reference)
//
#include <hip/hip_runtime.h>
#include <math.h>

#define WIDTH 512
#define LAYERS 6
#define HEADS 8
#define DH 64
#define T_DYN 16
#define NF 128
#define NFR 12            // N = N_FRAMES-1
#define BLK 146           // NF + T_DYN + 2
#define SEQ 1752          // NFR * BLK
#define BATCH 4
#define VOCAB 1024
#define MROWS (BATCH*SEQ)      // 7008
#define OUTROWS (BATCH*NFR*NF) // 6144

typedef __bf16 bf16_t;
typedef __bf16 bf16x8 __attribute__((ext_vector_type(8)));
typedef __bf16 bf16x4 __attribute__((ext_vector_type(4)));
typedef float f32x4 __attribute__((ext_vector_type(4)));

// ---------------- fp32 -> bf16 cast (weights, hoisted once) ----------------
__global__ __launch_bounds__(256) void cast_kernel(
    const float* __restrict__ in, bf16_t* __restrict__ out, int n4) {
    int i = blockIdx.x * 256 + threadIdx.x;
    if (i >= n4) return;
    float4 v = ((const float4*)in)[i];
    bf16x4 o = { (bf16_t)v.x, (bf16_t)v.y, (bf16_t)v.z, (bf16_t)v.w };
    *(bf16x4*)(out + (size_t)i * 4) = o;
}

// ---------------- embed: h = concat(x, delim, f, delim) + pos (fp32) ----------------
__global__ __launch_bounds__(256) void embed_kernel(
    const float* __restrict__ x, const float* __restrict__ f,
    const float* __restrict__ delim, float* __restrict__ h) {
    int idx = blockIdx.x * 256 + threadIdx.x;
    if (idx >= BATCH * SEQ * WIDTH) return;
    int w = idx & (WIDTH - 1);
    int bs = idx >> 9;
    int s = bs % SEQ;
    int b = bs / SEQ;
    int bi = s / BLK, r = s % BLK;
    float v;
    if (r < NF) {
        v = x[(((size_t)b * NFR + bi) * NF + r) * WIDTH + w];
    } else if (r == NF || r == BLK - 1) {
        v = delim[w];
    } else {
        v = f[(((size_t)b * NFR + bi) * T_DYN + (r - NF - 1)) * WIDTH + w];
    }
    int j = w >> 1;
    float denom = powf(10000.f, (float)j * (1.f / 256.f));
    float ang = (float)s / denom;
    v += (w & 1) ? cosf(ang) : sinf(ang);
    h[idx] = v;
}

// ---------------- LN stats: per-row (mean, rstd), one wave per row ----------------
__global__ __launch_bounds__(256) void ln_stats_kernel(
    const float* __restrict__ h, float2* __restrict__ stats) {
    int row = blockIdx.x * 4 + (threadIdx.x >> 6);
    int lane = threadIdx.x & 63;
    const float* p = h + (size_t)row * WIDTH + lane * 8;
    float4 a = *(const float4*)p;
    float4 b = *(const float4*)(p + 4);
    float s = a.x + a.y + a.z + a.w + b.x + b.y + b.z + b.w;
    float q = a.x*a.x + a.y*a.y + a.z*a.z + a.w*a.w
            + b.x*b.x + b.y*b.y + b.z*b.z + b.w*b.w;
    #pragma unroll
    for (int o = 32; o > 0; o >>= 1) {
        s += __shfl_xor(s, o);
        q += __shfl_xor(q, o);
    }
    if (lane == 0) {
        float mean = s * (1.f / WIDTH);
        float var = q * (1.f / WIDTH) - mean * mean;
        float2 st; st.x = mean; st.y = rsqrtf(var + 1e-5f);
        stats[row] = st;
    }
}

// ---------------- fused bf16 MFMA GEMM: C[M,N] = A[M,K] @ W[N,K]^T + bias ----------------
// W is PRE-CAST bf16 (row-major [N,K]).
// A_MODE 0: A bf16 direct    A_MODE 1: Af fp32 + LN(stats,g,b) -> bf16
// A_MODE 2: Af fp32 with head row-remap (gather) -> bf16
// C_MODE 0: fp32 store   C_MODE 1: gelu -> bf16 (LDS restage)   C_MODE 2: fp32 accumulate
//   (SPLIT==1: plain +=; SPLIT>1: unsafeAtomicAdd, bias applied by split 0 only)
// C_MODE 3: bf16 (LDS restage)
#define TM 128
#define TN 128
#define TK 32
#define CPAD 68   // restage row stride (bf16): 136B -> <=2-way banks both directions

template<int A_MODE, int C_MODE, int SPLIT>
__global__ __launch_bounds__(256) void gemm_f(
    const bf16_t* __restrict__ A, const float* __restrict__ Af,
    const float2* __restrict__ stats, const float* __restrict__ lng, const float* __restrict__ lnb,
    const bf16_t* __restrict__ Wb, const float* __restrict__ bias,
    float* __restrict__ Cf, bf16_t* __restrict__ Cb,
    int M, int N, int K) {
    constexpr int SMEM_SIZE = (C_MODE == 1 || C_MODE == 3) ? (4 * 64 * CPAD * 2) : (TM * TK * 2 + TN * TK * 2);
    __shared__ __align__(16) char smem[SMEM_SIZE];
    bf16_t* As = (bf16_t*)smem;
    bf16_t* Ws = As + TM * TK;

    int tid = threadIdx.x;
    int bm = blockIdx.y * TM, bn = blockIdx.x * TN;
    int ks = (SPLIT > 1) ? blockIdx.z * (K / SPLIT) : 0;
    int ke = (SPLIT > 1) ? ks + K / SPLIT : K;
    int lane = tid & 63, wid = tid >> 6;
    int wy = wid >> 1, wx = wid & 1;
    int lr = lane & 15, lq = lane >> 4;
    f32x4 acc[4][4];
    #pragma unroll
    for (int i = 0; i < 4; i++)
        #pragma unroll
        for (int j = 0; j < 4; j++)
            acc[i][j] = (f32x4){0.f, 0.f, 0.f, 0.f};

    int srow = tid >> 2;   // 0..63
    int sc_  = tid & 3;    // k-chunk 0..3 (8 elements each)

    // per-row hoisted A state (rows srow and srow+64)
    float2 st[2];
    const float* arow[2];
    const bf16_t* arow_bf[2];
    #pragma unroll
    for (int it = 0; it < 2; it++) {
        int gm = bm + srow + it * 64;
        if (A_MODE == 0) {
            arow_bf[it] = A + (size_t)gm * K;
        } else if (A_MODE == 1) {
            st[it] = stats[gm];
            arow[it] = Af + (size_t)gm * K;
        } else {
            int bb = gm / (NFR * NF);
            int rem = gm - bb * (NFR * NF);
            int n = rem >> 7, ii = rem & 127;
            arow[it] = Af + ((size_t)(bb * SEQ + n * BLK + ii)) * K;
        }
    }

    for (int k0 = ks; k0 < ke; k0 += TK) {
        float gv[8], bv[8];
        if (A_MODE == 1) {
            const float* gp = lng + k0 + sc_ * 8;
            const float* bp = lnb + k0 + sc_ * 8;
            float4 g0 = *(const float4*)gp, g1 = *(const float4*)(gp + 4);
            float4 b0 = *(const float4*)bp, b1 = *(const float4*)(bp + 4);
            gv[0]=g0.x; gv[1]=g0.y; gv[2]=g0.z; gv[3]=g0.w; gv[4]=g1.x; gv[5]=g1.y; gv[6]=g1.z; gv[7]=g1.w;
            bv[0]=b0.x; bv[1]=b0.y; bv[2]=b0.z; bv[3]=b0.w; bv[4]=b1.x; bv[5]=b1.y; bv[6]=b1.z; bv[7]=b1.w;
        }
        #pragma unroll
        for (int it = 0; it < 2; it++) {
            int row = srow + it * 64;
            int swz = (sc_ + (row >> 1)) & 3;
            bf16x8 av;
            if (A_MODE == 0) {
                av = *(const bf16x8*)(arow_bf[it] + k0 + sc_ * 8);
            } else if (A_MODE == 1) {
                const float* ap = arow[it] + k0 + sc_ * 8;
                float4 p0 = *(const float4*)ap, p1 = *(const float4*)(ap + 4);
                float mean = st[it].x, rstd = st[it].y;
                float t0 = (p0.x - mean) * rstd, t1 = (p0.y - mean) * rstd;
                float t2 = (p0.z - mean) * rstd, t3 = (p0.w - mean) * rstd;
                float t4 = (p1.x - mean) * rstd, t5 = (p1.y - mean) * rstd;
                float t6 = (p1.z - mean) * rstd, t7 = (p1.w - mean) * rstd;
                av[0] = (bf16_t)(t0 * gv[0] + bv[0]); av[1] = (bf16_t)(t1 * gv[1] + bv[1]);
                av[2] = (bf16_t)(t2 * gv[2] + bv[2]); av[3] = (bf16_t)(t3 * gv[3] + bv[3]);
                av[4] = (bf16_t)(t4 * gv[4] + bv[4]); av[5] = (bf16_t)(t5 * gv[5] + bv[5]);
                av[6] = (bf16_t)(t6 * gv[6] + bv[6]); av[7] = (bf16_t)(t7 * gv[7] + bv[7]);
            } else {
                const float* ap = arow[it] + k0 + sc_ * 8;
                float4 p0 = *(const float4*)ap, p1 = *(const float4*)(ap + 4);
                av[0] = (bf16_t)p0.x; av[1] = (bf16_t)p0.y; av[2] = (bf16_t)p0.z; av[3] = (bf16_t)p0.w;
                av[4] = (bf16_t)p1.x; av[5] = (bf16_t)p1.y; av[6] = (bf16_t)p1.z; av[7] = (bf16_t)p1.w;
            }
            *(bf16x8*)(As + row * TK + swz * 8) = av;

            bf16x8 wv = *(const bf16x8*)(Wb + (size_t)(bn + row) * K + k0 + sc_ * 8);
            *(bf16x8*)(Ws + row * TK + swz * 8) = wv;
        }
        __syncthreads();
        bf16x8 af[4], bfr[4];
        #pragma unroll
        for (int i = 0; i < 4; i++) {
            int rowa = wy * 64 + i * 16 + lr;
            int swza = (lq + (rowa >> 1)) & 3;
            af[i] = *(const bf16x8*)(As + rowa * TK + swza * 8);
            int rowb = wx * 64 + i * 16 + lr;
            int swzb = (lq + (rowb >> 1)) & 3;
            bfr[i] = *(const bf16x8*)(Ws + rowb * TK + swzb * 8);
        }
        #pragma unroll
        for (int i = 0; i < 4; i++)
            #pragma unroll
            for (int j = 0; j < 4; j++)
                acc[i][j] = __builtin_amdgcn_mfma_f32_16x16x32_bf16(af[i], bfr[j], acc[i][j], 0, 0, 0);
        __syncthreads();
    }

    if (C_MODE == 1 || C_MODE == 3) {
        // restage through per-wave LDS, then full-line bf16x8 stores
        bf16_t* Cw = (bf16_t*)smem + wid * 64 * CPAD;
        #pragma unroll
        for (int j = 0; j < 4; j++) {
            int col = bn + wx * 64 + j * 16 + lr;
            float bj = bias ? bias[col] : 0.f;
            #pragma unroll
            for (int i = 0; i < 4; i++) {
                #pragma unroll
                for (int r = 0; r < 4; r++) {
                    float v = acc[i][j][r] + bj;
                    if (C_MODE == 1) v = 0.5f * v * (1.f + erff(v * 0.70710678118654752f));
                    Cw[(i * 16 + lq * 4 + r) * CPAD + j * 16 + lr] = (bf16_t)v;
                }
            }
        }
        // wave-private region: no barrier needed
        #pragma unroll
        for (int it2 = 0; it2 < 8; it2++) {
            int row_l = (lane >> 3) + it2 * 8;
            int seg = lane & 7;
            int gm = bm + wy * 64 + row_l;
            if (gm < M)
                *(bf16x8*)(Cb + (size_t)gm * N + bn + wx * 64 + seg * 8) =
                    *(const bf16x8*)(Cw + row_l * CPAD + seg * 8);
        }
    } else {
        #pragma unroll
        for (int j = 0; j < 4; j++) {
            int col = bn + wx * 64 + j * 16 + lr;
            float bj = bias ? bias[col] : 0.f;
            if (SPLIT > 1 && blockIdx.z != 0) bj = 0.f;
            #pragma unroll
            for (int i = 0; i < 4; i++) {
                int rbase = bm + wy * 64 + i * 16 + lq * 4;
                #pragma unroll
                for (int r = 0; r < 4; r++) {
                    int gm = rbase + r;
                    if (gm >= M) continue;
                    float v = acc[i][j][r] + bj;
                    if (C_MODE == 2) {
                        if (SPLIT > 1) unsafeAtomicAdd(&Cf[(size_t)gm * N + col], v);
                        else           Cf[(size_t)gm * N + col] += v;
                    } else {
                        Cf[(size_t)gm * N + col] = v;
                    }
                }
            }
        }
    }
}

// ---------------- structured-mask attention (MFMA) ----------------
__device__ __forceinline__ int key_of(int t, int bi) {
    if (bi > 0) { if (t == 0) return bi * BLK - 1; t -= 1; }
    if (t < NF) return bi * BLK + t;
    t -= NF;
    int j = t / 17, r = t % 17;
    return j * BLK + NF + r;
}

#define KC 64           // keys per chunk
#define KR 72           // padded LDS row length

// block = (bi, h, b), 256 threads = 4 waves; wave w owns q rows [w*32, w*32+32)
// also copies this (bi,h,b)'s 18 self-only rows (o = v) at entry
__global__ __launch_bounds__(256) void attn_mfma(
    const bf16_t* __restrict__ qkv, bf16_t* __restrict__ o) {
    int bi = blockIdx.x;
    int h = blockIdx.y, b = blockIdx.z;
    int tid = threadIdx.x;
    int lane = tid & 63, wid = tid >> 6;
    int col = lane & 15, lq = lane >> 4;
    int qr0 = wid * 32;
    const bf16_t* base = qkv + (size_t)b * SEQ * (3 * WIDTH);

    __shared__ bf16_t Ks[KC * KR];        // [key][dim], pad 72
    __shared__ bf16_t Vt[DH * KR];        // [dim][key], pad 72
    __shared__ bf16_t Ps[4][32 * KR];     // per-wave P / O staging
    __shared__ int slist[352];

    // self-only rows for this (bi,h,b): 18 rows x 64 dims = 144 bf16x8 copies
    if (tid < 144) {
        int row = NF + (tid >> 3), g = tid & 7;
        int s = bi * BLK + row;
        *(bf16x8*)(o + ((size_t)(b * SEQ) + s) * WIDTH + h * DH + g * 8) =
            *(const bf16x8*)(base + (size_t)s * (3 * WIDTH) + 2 * WIDTH + h * DH + g * 8);
    }

    int na = (bi > 0 ? 1 : 0) + NF + 17 * (bi + 1);   // <= 333
    for (int t = tid; t < na; t += 256) slist[t] = key_of(t, bi);

    bf16x8 af_q[2][2];
    #pragma unroll
    for (int i = 0; i < 2; i++) {
        int s = bi * BLK + qr0 + i * 16 + col;
        const bf16_t* qp = base + (size_t)s * (3 * WIDTH) + h * DH;
        #pragma unroll
        for (int m = 0; m < 2; m++)
            af_q[i][m] = *(const bf16x8*)(qp + m * 32 + lq * 8);
    }

    f32x4 Oacc[2][4];
    #pragma unroll
    for (int i = 0; i < 2; i++)
        #pragma unroll
        for (int od = 0; od < 4; od++)
            Oacc[i][od] = (f32x4){0.f, 0.f, 0.f, 0.f};
    float m_r[2][4], l_r[2][4];
    #pragma unroll
    for (int i = 0; i < 2; i++)
        #pragma unroll
        for (int r = 0; r < 4; r++) { m_r[i][r] = -INFINITY; l_r[i][r] = 0.f; }

    __syncthreads();   // slist ready

    int nch = (na + KC - 1) / KC;
    const bf16_t z0 = (bf16_t)0.f;
    for (int ci = 0; ci < nch; ci++) {
        int kbase = ci * KC;
        #pragma unroll
        for (int it = 0; it < 2; it++) {
            int idx = tid + it * 256;      // 0..511
            int key = idx >> 3, g = idx & 7;
            int tkey = kbase + key;
            bf16x8 kv = {z0,z0,z0,z0,z0,z0,z0,z0};
            bf16x8 vv = kv;
            if (tkey < na) {
                int sk = slist[tkey];
                const bf16_t* kp = base + (size_t)sk * (3 * WIDTH) + WIDTH + h * DH + g * 8;
                kv = *(const bf16x8*)kp;
                vv = *(const bf16x8*)(kp + WIDTH);
            }
            *(bf16x8*)(Ks + key * KR + g * 8) = kv;
            #pragma unroll
            for (int j = 0; j < 8; j++) Vt[(g * 8 + j) * KR + key] = vv[j];
        }
        __syncthreads();

        f32x4 Sacc[2][4];
        #pragma unroll
        for (int i = 0; i < 2; i++)
            #pragma unroll
            for (int kj = 0; kj < 4; kj++)
                Sacc[i][kj] = (f32x4){0.f, 0.f, 0.f, 0.f};
        #pragma unroll
        for (int m = 0; m < 2; m++) {
            #pragma unroll
            for (int kj = 0; kj < 4; kj++) {
                bf16x8 bf_k = *(const bf16x8*)(Ks + (kj * 16 + col) * KR + m * 32 + lq * 8);
                #pragma unroll
                for (int i = 0; i < 2; i++)
                    Sacc[i][kj] = __builtin_amdgcn_mfma_f32_16x16x32_bf16(af_q[i][m], bf_k, Sacc[i][kj], 0, 0, 0);
            }
        }

        float alpha_[2][4];
        #pragma unroll
        for (int i = 0; i < 2; i++) {
            #pragma unroll
            for (int r = 0; r < 4; r++) {
                #pragma unroll
                for (int kj = 0; kj < 4; kj++) {
                    int kidx = kbase + kj * 16 + col;
                    float s = Sacc[i][kj][r] * 0.125f;
                    Sacc[i][kj][r] = (kidx < na) ? s : -INFINITY;
                }
                float mx = fmaxf(fmaxf(Sacc[i][0][r], Sacc[i][1][r]),
                                 fmaxf(Sacc[i][2][r], Sacc[i][3][r]));
                mx = fmaxf(mx, __shfl_xor(mx, 1));
                mx = fmaxf(mx, __shfl_xor(mx, 2));
                mx = fmaxf(mx, __shfl_xor(mx, 4));
                mx = fmaxf(mx, __shfl_xor(mx, 8));
                float mn = fmaxf(m_r[i][r], mx);
                float al = __expf(m_r[i][r] - mn);
                float ps = 0.f;
                #pragma unroll
                for (int kj = 0; kj < 4; kj++) {
                    float p = __expf(Sacc[i][kj][r] - mn);
                    Sacc[i][kj][r] = p;
                    ps += p;
                }
                ps += __shfl_xor(ps, 1);
                ps += __shfl_xor(ps, 2);
                ps += __shfl_xor(ps, 4);
                ps += __shfl_xor(ps, 8);
                l_r[i][r] = l_r[i][r] * al + ps;
                m_r[i][r] = mn;
                alpha_[i][r] = al;
            }
        }
        #pragma unroll
        for (int i = 0; i < 2; i++)
            #pragma unroll
            for (int od = 0; od < 4; od++)
                #pragma unroll
                for (int r = 0; r < 4; r++)
                    Oacc[i][od][r] *= alpha_[i][r];

        bf16_t* Pw = Ps[wid];
        #pragma unroll
        for (int i = 0; i < 2; i++)
            #pragma unroll
            for (int kj = 0; kj < 4; kj++)
                #pragma unroll
                for (int r = 0; r < 4; r++)
                    Pw[(i * 16 + lq * 4 + r) * KR + kj * 16 + col] = (bf16_t)Sacc[i][kj][r];
        __syncthreads();

        #pragma unroll
        for (int m = 0; m < 2; m++) {
            bf16x8 afp[2];
            #pragma unroll
            for (int i = 0; i < 2; i++)
                afp[i] = *(const bf16x8*)(Pw + (i * 16 + col) * KR + m * 32 + lq * 8);
            #pragma unroll
            for (int od = 0; od < 4; od++) {
                bf16x8 vf = *(const bf16x8*)(Vt + (od * 16 + col) * KR + m * 32 + lq * 8);
                #pragma unroll
                for (int i = 0; i < 2; i++)
                    Oacc[i][od] = __builtin_amdgcn_mfma_f32_16x16x32_bf16(afp[i], vf, Oacc[i][od], 0, 0, 0);
            }
        }
        __syncthreads();
    }

    bf16_t* Pw = Ps[wid];
    float inv[2][4];
    #pragma unroll
    for (int i = 0; i < 2; i++)
        #pragma unroll
        for (int r = 0; r < 4; r++) inv[i][r] = 1.f / l_r[i][r];
    #pragma unroll
    for (int i = 0; i < 2; i++)
        #pragma unroll
        for (int od = 0; od < 4; od++)
            #pragma unroll
            for (int r = 0; r < 4; r++)
                Pw[(i * 16 + lq * 4 + r) * KR + od * 16 + col] = (bf16_t)(Oacc[i][od][r] * inv[i][r]);
    __syncthreads();
    #pragma unroll
    for (int it = 0; it < 4; it++) {
        int idx = lane + it * 64;
        int row = idx >> 3, g = idx & 7;
        int gs = bi * BLK + qr0 + row;
        *(bf16x8*)(o + ((size_t)(b * SEQ + gs)) * WIDTH + h * DH + g * 8) =
            *(const bf16x8*)(Pw + row * KR + g * 8);
    }
}

extern "C" void kernel_launch(void* const* d_in, const int* in_sizes, int n_in,
                              void* d_out, int out_size, void* d_ws, size_t ws_size,
                              hipStream_t stream) {
    const float* x     = (const float*)d_in[0];
    const float* f     = (const float*)d_in[1];
    const float* delim = (const float*)d_in[2];
    const float* ln1_s = (const float*)d_in[3];
    const float* ln1_b = (const float*)d_in[4];
    const float* w_qkv = (const float*)d_in[5];
    const float* b_qkv = (const float*)d_in[6];
    const float* w_out = (const float*)d_in[7];
    const float* b_out = (const float*)d_in[8];
    const float* ln2_s = (const float*)d_in[9];
    const float* ln2_b = (const float*)d_in[10];
    const float* w_fc  = (const float*)d_in[11];
    const float* b_fc  = (const float*)d_in[12];
    const float* w_pr  = (const float*)d_in[13];
    const float* b_pr  = (const float*)d_in[14];
    const float* w_hd  = (const float*)d_in[15];
    float* out = (float*)d_out;

    // workspace layout (~82 MB total):
    // h fp32 (14.35) | big_bf (28.7; qkv uses 1536-wide, attn-out o_bf aliases the tail)
    // | stats (56 KB + 64 KB slack) | bf16 weights (38.8)
    char* base = (char*)d_ws;
    float*  h      = (float*)base;    base += (size_t)MROWS * WIDTH * 4;
    bf16_t* big_bf = (bf16_t*)base;   base += (size_t)MROWS * 2048 * 2;
    bf16_t* o_bf   = big_bf + (size_t)MROWS * 1536;   // tail alias: MROWS*512 bf16
    float2* stats  = (float2*)base;   base += (size_t)MROWS * 8 + 65536;
    bf16_t* wi_bf  = (bf16_t*)base;   base += (size_t)LAYERS * 1536 * 512 * 2;
    bf16_t* wo_bf  = (bf16_t*)base;   base += (size_t)LAYERS * 512 * 512 * 2;
    bf16_t* wfc_bf = (bf16_t*)base;   base += (size_t)LAYERS * 2048 * 512 * 2;
    bf16_t* wpr_bf = (bf16_t*)base;   base += (size_t)LAYERS * 512 * 2048 * 2;
    bf16_t* wh_bf  = (bf16_t*)base;   base += (size_t)VOCAB * 512 * 2;

    // hoisted weight casts (once per launch)
    cast_kernel<<<LAYERS * 1536 * 512 / 1024, 256, 0, stream>>>(w_qkv, wi_bf, LAYERS * 1536 * 512 / 4);
    cast_kernel<<<LAYERS * 512 * 512 / 1024, 256, 0, stream>>>(w_out, wo_bf, LAYERS * 512 * 512 / 4);
    cast_kernel<<<LAYERS * 2048 * 512 / 1024, 256, 0, stream>>>(w_fc, wfc_bf, LAYERS * 2048 * 512 / 4);
    cast_kernel<<<LAYERS * 512 * 2048 / 1024, 256, 0, stream>>>(w_pr, wpr_bf, LAYERS * 512 * 2048 / 4);
    cast_kernel<<<VOCAB * 512 / 1024, 256, 0, stream>>>(w_hd, wh_bf, VOCAB * 512 / 4);

    embed_kernel<<<(BATCH * SEQ * WIDTH) / 256, 256, 0, stream>>>(x, f, delim, h);

    // head output will be accumulated atomically (split-K) -> zero it now
    hipMemsetAsync(d_out, 0, (size_t)out_size * 4, stream);

    const int MT = (MROWS + TM - 1) / TM;   // 55
    for (int l = 0; l < LAYERS; l++) {
        ln_stats_kernel<<<MROWS / 4, 256, 0, stream>>>(h, stats);
        gemm_f<1, 3, 1><<<dim3(1536 / TN, MT), 256, 0, stream>>>(
            nullptr, h, stats, ln1_s + l * WIDTH, ln1_b + l * WIDTH,
            wi_bf + (size_t)l * 1536 * 512, b_qkv + (size_t)l * 1536,
            nullptr, big_bf, MROWS, 1536, 512);
        attn_mfma<<<dim3(NFR, HEADS, BATCH), 256, 0, stream>>>(big_bf, o_bf);
        gemm_f<0, 2, 2><<<dim3(512 / TN, MT, 2), 256, 0, stream>>>(
            o_bf, nullptr, nullptr, nullptr, nullptr,
            wo_bf + (size_t)l * 512 * 512, b_out + (size_t)l * 512,
            h, nullptr, MROWS, 512, 512);
        ln_stats_kernel<<<MROWS / 4, 256, 0, stream>>>(h, stats);
        gemm_f<1, 1, 1><<<dim3(2048 / TN, MT), 256, 0, stream>>>(
            nullptr, h, stats, ln2_s + l * WIDTH, ln2_b + l * WIDTH,
            wfc_bf + (size_t)l * 2048 * 512, b_fc + (size_t)l * 2048,
            nullptr, big_bf, MROWS, 2048, 512);
        gemm_f<0, 2, 4><<<dim3(512 / TN, MT, 4), 256, 0, stream>>>(
            big_bf, nullptr, nullptr, nullptr, nullptr,
            wpr_bf + (size_t)l * 512 * 2048, b_pr + (size_t)l * 512,
            h, nullptr, MROWS, 512, 2048);
    }

    gemm_f<2, 2, 2><<<dim3(VOCAB / TN, OUTROWS / TM, 2), 256, 0, stream>>>(
        nullptr, h, nullptr, nullptr, nullptr,
        wh_bf, nullptr, out, nullptr, OUTROWS, VOCAB, 512);
}

// Round 7
// 1390.548 us; speedup vs baseline: 1.1307x; 1.1307x over previous
//
#include <hip/hip_runtime.h>
#include <math.h>

#define WIDTH 512
#define LAYERS 6
#define HEADS 8
#define DH 64
#define T_DYN 16
#define NF 128
#define NFR 12            // N = N_FRAMES-1
#define BLK 146           // NF + T_DYN + 2
#define SEQ 1752          // NFR * BLK
#define BATCH 4
#define VOCAB 1024
#define MROWS (BATCH*SEQ)      // 7008
#define OUTROWS (BATCH*NFR*NF) // 6144

typedef __bf16 bf16_t;
typedef __bf16 bf16x8 __attribute__((ext_vector_type(8)));
typedef __bf16 bf16x4 __attribute__((ext_vector_type(4)));
typedef float f32x4 __attribute__((ext_vector_type(4)));

// ---------------- fp32 -> bf16 cast (weights, hoisted once) ----------------
__global__ __launch_bounds__(256) void cast_kernel(
    const float* __restrict__ in, bf16_t* __restrict__ out, int n4) {
    int i = blockIdx.x * 256 + threadIdx.x;
    if (i >= n4) return;
    float4 v = ((const float4*)in)[i];
    bf16x4 o = { (bf16_t)v.x, (bf16_t)v.y, (bf16_t)v.z, (bf16_t)v.w };
    *(bf16x4*)(out + (size_t)i * 4) = o;
}

// ---------------- embed: h = concat(x, delim, f, delim) + pos (fp32) ----------------
__global__ __launch_bounds__(256) void embed_kernel(
    const float* __restrict__ x, const float* __restrict__ f,
    const float* __restrict__ delim, float* __restrict__ h) {
    int idx = blockIdx.x * 256 + threadIdx.x;
    if (idx >= BATCH * SEQ * WIDTH) return;
    int w = idx & (WIDTH - 1);
    int bs = idx >> 9;
    int s = bs % SEQ;
    int b = bs / SEQ;
    int bi = s / BLK, r = s % BLK;
    float v;
    if (r < NF) {
        v = x[(((size_t)b * NFR + bi) * NF + r) * WIDTH + w];
    } else if (r == NF || r == BLK - 1) {
        v = delim[w];
    } else {
        v = f[(((size_t)b * NFR + bi) * T_DYN + (r - NF - 1)) * WIDTH + w];
    }
    int j = w >> 1;
    float denom = powf(10000.f, (float)j * (1.f / 256.f));
    float ang = (float)s / denom;
    v += (w & 1) ? cosf(ang) : sinf(ang);
    h[idx] = v;
}

// ---------------- LN stats: per-row (mean, rstd), one wave per row ----------------
__global__ __launch_bounds__(256) void ln_stats_kernel(
    const float* __restrict__ h, float2* __restrict__ stats) {
    int row = blockIdx.x * 4 + (threadIdx.x >> 6);
    int lane = threadIdx.x & 63;
    const float* p = h + (size_t)row * WIDTH + lane * 8;
    float4 a = *(const float4*)p;
    float4 b = *(const float4*)(p + 4);
    float s = a.x + a.y + a.z + a.w + b.x + b.y + b.z + b.w;
    float q = a.x*a.x + a.y*a.y + a.z*a.z + a.w*a.w
            + b.x*b.x + b.y*b.y + b.z*b.z + b.w*b.w;
    #pragma unroll
    for (int o = 32; o > 0; o >>= 1) {
        s += __shfl_xor(s, o);
        q += __shfl_xor(q, o);
    }
    if (lane == 0) {
        float mean = s * (1.f / WIDTH);
        float var = q * (1.f / WIDTH) - mean * mean;
        float2 st; st.x = mean; st.y = rsqrtf(var + 1e-5f);
        stats[row] = st;
    }
}

// ---------------- fused bf16 MFMA GEMM: C[M,N] = A[M,K] @ W[N,K]^T + bias ----------------
// W is PRE-CAST bf16 (row-major [N,K]).  TNV = N tile (128 or 64).
// A_MODE 0: A bf16 direct    A_MODE 1: Af fp32 + LN(stats,g,b) -> bf16
// A_MODE 2: Af fp32 with head row-remap (gather) -> bf16
// C_MODE 0: fp32 store   C_MODE 1: gelu -> bf16 (LDS restage, TNV=128 only)
// C_MODE 2: fp32 +=      C_MODE 3: bf16 (LDS restage, TNV=128 only)
#define TM 128
#define TK 32
#define CPAD 68   // restage row stride (bf16): 136B -> <=2-way banks both directions

template<int A_MODE, int C_MODE, int TNV>
__global__ __launch_bounds__(256) void gemm_f(
    const bf16_t* __restrict__ A, const float* __restrict__ Af,
    const float2* __restrict__ stats, const float* __restrict__ lng, const float* __restrict__ lnb,
    const bf16_t* __restrict__ Wb, const float* __restrict__ bias,
    float* __restrict__ Cf, bf16_t* __restrict__ Cb,
    int M, int N, int K) {
    constexpr int RI = (TNV == 128) ? 4 : 2;   // row subtiles per wave
    constexpr int SMEM_SIZE = (C_MODE == 1 || C_MODE == 3) ? (4 * 64 * CPAD * 2)
                                                           : ((TM + TNV) * TK * 2);
    __shared__ __align__(16) char smem[SMEM_SIZE];
    bf16_t* As = (bf16_t*)smem;
    bf16_t* Ws = As + TM * TK;

    int tid = threadIdx.x;
    int bm = blockIdx.y * TM, bn = blockIdx.x * TNV;
    int lane = tid & 63, wid = tid >> 6;
    int wy, wx, wrb;
    if (TNV == 128) { wy = wid >> 1; wx = wid & 1; wrb = wy * 64; }
    else            { wy = wid;      wx = 0;       wrb = wy * 32; }
    int lr = lane & 15, lq = lane >> 4;
    f32x4 acc[RI][4];
    #pragma unroll
    for (int i = 0; i < RI; i++)
        #pragma unroll
        for (int j = 0; j < 4; j++)
            acc[i][j] = (f32x4){0.f, 0.f, 0.f, 0.f};

    int srow = tid >> 2;   // 0..63
    int sc_  = tid & 3;    // k-chunk 0..3 (8 elements each)

    // per-row hoisted A state (rows srow and srow+64)
    float2 st[2];
    const float* arow[2];
    const bf16_t* arow_bf[2];
    #pragma unroll
    for (int it = 0; it < 2; it++) {
        int gm = bm + srow + it * 64;
        if (A_MODE == 0) {
            arow_bf[it] = A + (size_t)gm * K;
        } else if (A_MODE == 1) {
            st[it] = stats[gm];
            arow[it] = Af + (size_t)gm * K;
        } else {
            int bb = gm / (NFR * NF);
            int rem = gm - bb * (NFR * NF);
            int n = rem >> 7, ii = rem & 127;
            arow[it] = Af + ((size_t)(bb * SEQ + n * BLK + ii)) * K;
        }
    }

    for (int k0 = 0; k0 < K; k0 += TK) {
        float gv[8], bv[8];
        if (A_MODE == 1) {
            const float* gp = lng + k0 + sc_ * 8;
            const float* bp = lnb + k0 + sc_ * 8;
            float4 g0 = *(const float4*)gp, g1 = *(const float4*)(gp + 4);
            float4 b0 = *(const float4*)bp, b1 = *(const float4*)(bp + 4);
            gv[0]=g0.x; gv[1]=g0.y; gv[2]=g0.z; gv[3]=g0.w; gv[4]=g1.x; gv[5]=g1.y; gv[6]=g1.z; gv[7]=g1.w;
            bv[0]=b0.x; bv[1]=b0.y; bv[2]=b0.z; bv[3]=b0.w; bv[4]=b1.x; bv[5]=b1.y; bv[6]=b1.z; bv[7]=b1.w;
        }
        #pragma unroll
        for (int it = 0; it < 2; it++) {
            int row = srow + it * 64;
            int swz = (sc_ + (row >> 1)) & 3;
            bf16x8 av;
            if (A_MODE == 0) {
                av = *(const bf16x8*)(arow_bf[it] + k0 + sc_ * 8);
            } else if (A_MODE == 1) {
                const float* ap = arow[it] + k0 + sc_ * 8;
                float4 p0 = *(const float4*)ap, p1 = *(const float4*)(ap + 4);
                float mean = st[it].x, rstd = st[it].y;
                float t0 = (p0.x - mean) * rstd, t1 = (p0.y - mean) * rstd;
                float t2 = (p0.z - mean) * rstd, t3 = (p0.w - mean) * rstd;
                float t4 = (p1.x - mean) * rstd, t5 = (p1.y - mean) * rstd;
                float t6 = (p1.z - mean) * rstd, t7 = (p1.w - mean) * rstd;
                av[0] = (bf16_t)(t0 * gv[0] + bv[0]); av[1] = (bf16_t)(t1 * gv[1] + bv[1]);
                av[2] = (bf16_t)(t2 * gv[2] + bv[2]); av[3] = (bf16_t)(t3 * gv[3] + bv[3]);
                av[4] = (bf16_t)(t4 * gv[4] + bv[4]); av[5] = (bf16_t)(t5 * gv[5] + bv[5]);
                av[6] = (bf16_t)(t6 * gv[6] + bv[6]); av[7] = (bf16_t)(t7 * gv[7] + bv[7]);
            } else {
                const float* ap = arow[it] + k0 + sc_ * 8;
                float4 p0 = *(const float4*)ap, p1 = *(const float4*)(ap + 4);
                av[0] = (bf16_t)p0.x; av[1] = (bf16_t)p0.y; av[2] = (bf16_t)p0.z; av[3] = (bf16_t)p0.w;
                av[4] = (bf16_t)p1.x; av[5] = (bf16_t)p1.y; av[6] = (bf16_t)p1.z; av[7] = (bf16_t)p1.w;
            }
            *(bf16x8*)(As + row * TK + swz * 8) = av;
        }
        #pragma unroll
        for (int itw = 0; itw < TNV / 64; itw++) {
            int row = srow + itw * 64;
            int swz = (sc_ + (row >> 1)) & 3;
            bf16x8 wv = *(const bf16x8*)(Wb + (size_t)(bn + row) * K + k0 + sc_ * 8);
            *(bf16x8*)(Ws + row * TK + swz * 8) = wv;
        }
        __syncthreads();
        bf16x8 af[RI], bfr[4];
        #pragma unroll
        for (int i = 0; i < RI; i++) {
            int rowa = wrb + i * 16 + lr;
            int swza = (lq + (rowa >> 1)) & 3;
            af[i] = *(const bf16x8*)(As + rowa * TK + swza * 8);
        }
        #pragma unroll
        for (int j = 0; j < 4; j++) {
            int rowb = wx * 64 + j * 16 + lr;
            int swzb = (lq + (rowb >> 1)) & 3;
            bfr[j] = *(const bf16x8*)(Ws + rowb * TK + swzb * 8);
        }
        #pragma unroll
        for (int i = 0; i < RI; i++)
            #pragma unroll
            for (int j = 0; j < 4; j++)
                acc[i][j] = __builtin_amdgcn_mfma_f32_16x16x32_bf16(af[i], bfr[j], acc[i][j], 0, 0, 0);
        __syncthreads();
    }

    if constexpr (C_MODE == 1 || C_MODE == 3) {
        // restage through per-wave LDS, then full-line bf16x8 stores (TNV==128)
        bf16_t* Cw = (bf16_t*)smem + wid * 64 * CPAD;
        #pragma unroll
        for (int j = 0; j < 4; j++) {
            int col = bn + wx * 64 + j * 16 + lr;
            float bj = bias ? bias[col] : 0.f;
            #pragma unroll
            for (int i = 0; i < RI; i++) {
                #pragma unroll
                for (int r = 0; r < 4; r++) {
                    float v = acc[i][j][r] + bj;
                    if (C_MODE == 1) v = 0.5f * v * (1.f + erff(v * 0.70710678118654752f));
                    Cw[(i * 16 + lq * 4 + r) * CPAD + j * 16 + lr] = (bf16_t)v;
                }
            }
        }
        // wave-private region: no barrier needed
        #pragma unroll
        for (int it2 = 0; it2 < 8; it2++) {
            int row_l = (lane >> 3) + it2 * 8;
            int seg = lane & 7;
            int gm = bm + wy * 64 + row_l;
            if (gm < M)
                *(bf16x8*)(Cb + (size_t)gm * N + bn + wx * 64 + seg * 8) =
                    *(const bf16x8*)(Cw + row_l * CPAD + seg * 8);
        }
    } else {
        #pragma unroll
        for (int j = 0; j < 4; j++) {
            int col = bn + wx * 64 + j * 16 + lr;
            float bj = bias ? bias[col] : 0.f;
            #pragma unroll
            for (int i = 0; i < RI; i++) {
                int rbase = bm + wrb + i * 16 + lq * 4;
                #pragma unroll
                for (int r = 0; r < 4; r++) {
                    int gm = rbase + r;
                    if (gm >= M) continue;
                    float v = acc[i][j][r] + bj;
                    if (C_MODE == 2) Cf[(size_t)gm * N + col] += v;
                    else             Cf[(size_t)gm * N + col] = v;
                }
            }
        }
    }
}

// ---------------- structured-mask attention (MFMA) ----------------
__device__ __forceinline__ int key_of(int t, int bi) {
    if (bi > 0) { if (t == 0) return bi * BLK - 1; t -= 1; }
    if (t < NF) return bi * BLK + t;
    t -= NF;
    int j = t / 17, r = t % 17;
    return j * BLK + NF + r;
}

#define KC 64           // keys per chunk
#define KR 72           // padded LDS row length

// block = (bi, h, b), 256 threads = 4 waves; wave w owns q rows [w*32, w*32+32)
// also copies this (bi,h,b)'s 18 self-only rows (o = v) at entry
__global__ __launch_bounds__(256) void attn_mfma(
    const bf16_t* __restrict__ qkv, bf16_t* __restrict__ o) {
    int bi = blockIdx.x;
    int h = blockIdx.y, b = blockIdx.z;
    int tid = threadIdx.x;
    int lane = tid & 63, wid = tid >> 6;
    int col = lane & 15, lq = lane >> 4;
    int qr0 = wid * 32;
    const bf16_t* base = qkv + (size_t)b * SEQ * (3 * WIDTH);

    __shared__ bf16_t Ks[KC * KR];        // [key][dim], pad 72
    __shared__ bf16_t Vt[DH * KR];        // [dim][key], pad 72
    __shared__ bf16_t Ps[4][32 * KR];     // per-wave P / O staging
    __shared__ int slist[352];

    // self-only rows for this (bi,h,b): 18 rows x 64 dims = 144 bf16x8 copies
    if (tid < 144) {
        int row = NF + (tid >> 3), g = tid & 7;
        int s = bi * BLK + row;
        *(bf16x8*)(o + ((size_t)(b * SEQ) + s) * WIDTH + h * DH + g * 8) =
            *(const bf16x8*)(base + (size_t)s * (3 * WIDTH) + 2 * WIDTH + h * DH + g * 8);
    }

    int na = (bi > 0 ? 1 : 0) + NF + 17 * (bi + 1);   // <= 333
    for (int t = tid; t < na; t += 256) slist[t] = key_of(t, bi);

    bf16x8 af_q[2][2];
    #pragma unroll
    for (int i = 0; i < 2; i++) {
        int s = bi * BLK + qr0 + i * 16 + col;
        const bf16_t* qp = base + (size_t)s * (3 * WIDTH) + h * DH;
        #pragma unroll
        for (int m = 0; m < 2; m++)
            af_q[i][m] = *(const bf16x8*)(qp + m * 32 + lq * 8);
    }

    f32x4 Oacc[2][4];
    #pragma unroll
    for (int i = 0; i < 2; i++)
        #pragma unroll
        for (int od = 0; od < 4; od++)
            Oacc[i][od] = (f32x4){0.f, 0.f, 0.f, 0.f};
    float m_r[2][4], l_r[2][4];
    #pragma unroll
    for (int i = 0; i < 2; i++)
        #pragma unroll
        for (int r = 0; r < 4; r++) { m_r[i][r] = -INFINITY; l_r[i][r] = 0.f; }

    __syncthreads();   // slist ready

    int nch = (na + KC - 1) / KC;
    const bf16_t z0 = (bf16_t)0.f;
    for (int ci = 0; ci < nch; ci++) {
        int kbase = ci * KC;
        #pragma unroll
        for (int it = 0; it < 2; it++) {
            int idx = tid + it * 256;      // 0..511
            int key = idx >> 3, g = idx & 7;
            int tkey = kbase + key;
            bf16x8 kv = {z0,z0,z0,z0,z0,z0,z0,z0};
            bf16x8 vv = kv;
            if (tkey < na) {
                int sk = slist[tkey];
                const bf16_t* kp = base + (size_t)sk * (3 * WIDTH) + WIDTH + h * DH + g * 8;
                kv = *(const bf16x8*)kp;
                vv = *(const bf16x8*)(kp + WIDTH);
            }
            *(bf16x8*)(Ks + key * KR + g * 8) = kv;
            #pragma unroll
            for (int j = 0; j < 8; j++) Vt[(g * 8 + j) * KR + key] = vv[j];
        }
        __syncthreads();

        f32x4 Sacc[2][4];
        #pragma unroll
        for (int i = 0; i < 2; i++)
            #pragma unroll
            for (int kj = 0; kj < 4; kj++)
                Sacc[i][kj] = (f32x4){0.f, 0.f, 0.f, 0.f};
        #pragma unroll
        for (int m = 0; m < 2; m++) {
            #pragma unroll
            for (int kj = 0; kj < 4; kj++) {
                bf16x8 bf_k = *(const bf16x8*)(Ks + (kj * 16 + col) * KR + m * 32 + lq * 8);
                #pragma unroll
                for (int i = 0; i < 2; i++)
                    Sacc[i][kj] = __builtin_amdgcn_mfma_f32_16x16x32_bf16(af_q[i][m], bf_k, Sacc[i][kj], 0, 0, 0);
            }
        }

        float alpha_[2][4];
        #pragma unroll
        for (int i = 0; i < 2; i++) {
            #pragma unroll
            for (int r = 0; r < 4; r++) {
                #pragma unroll
                for (int kj = 0; kj < 4; kj++) {
                    int kidx = kbase + kj * 16 + col;
                    float s = Sacc[i][kj][r] * 0.125f;
                    Sacc[i][kj][r] = (kidx < na) ? s : -INFINITY;
                }
                float mx = fmaxf(fmaxf(Sacc[i][0][r], Sacc[i][1][r]),
                                 fmaxf(Sacc[i][2][r], Sacc[i][3][r]));
                mx = fmaxf(mx, __shfl_xor(mx, 1));
                mx = fmaxf(mx, __shfl_xor(mx, 2));
                mx = fmaxf(mx, __shfl_xor(mx, 4));
                mx = fmaxf(mx, __shfl_xor(mx, 8));
                float mn = fmaxf(m_r[i][r], mx);
                float al = __expf(m_r[i][r] - mn);
                float ps = 0.f;
                #pragma unroll
                for (int kj = 0; kj < 4; kj++) {
                    float p = __expf(Sacc[i][kj][r] - mn);
                    Sacc[i][kj][r] = p;
                    ps += p;
                }
                ps += __shfl_xor(ps, 1);
                ps += __shfl_xor(ps, 2);
                ps += __shfl_xor(ps, 4);
                ps += __shfl_xor(ps, 8);
                l_r[i][r] = l_r[i][r] * al + ps;
                m_r[i][r] = mn;
                alpha_[i][r] = al;
            }
        }
        #pragma unroll
        for (int i = 0; i < 2; i++)
            #pragma unroll
            for (int od = 0; od < 4; od++)
                #pragma unroll
                for (int r = 0; r < 4; r++)
                    Oacc[i][od][r] *= alpha_[i][r];

        bf16_t* Pw = Ps[wid];
        #pragma unroll
        for (int i = 0; i < 2; i++)
            #pragma unroll
            for (int kj = 0; kj < 4; kj++)
                #pragma unroll
                for (int r = 0; r < 4; r++)
                    Pw[(i * 16 + lq * 4 + r) * KR + kj * 16 + col] = (bf16_t)Sacc[i][kj][r];
        __syncthreads();

        #pragma unroll
        for (int m = 0; m < 2; m++) {
            bf16x8 afp[2];
            #pragma unroll
            for (int i = 0; i < 2; i++)
                afp[i] = *(const bf16x8*)(Pw + (i * 16 + col) * KR + m * 32 + lq * 8);
            #pragma unroll
            for (int od = 0; od < 4; od++) {
                bf16x8 vf = *(const bf16x8*)(Vt + (od * 16 + col) * KR + m * 32 + lq * 8);
                #pragma unroll
                for (int i = 0; i < 2; i++)
                    Oacc[i][od] = __builtin_amdgcn_mfma_f32_16x16x32_bf16(afp[i], vf, Oacc[i][od], 0, 0, 0);
            }
        }
        __syncthreads();
    }

    bf16_t* Pw = Ps[wid];
    float inv[2][4];
    #pragma unroll
    for (int i = 0; i < 2; i++)
        #pragma unroll
        for (int r = 0; r < 4; r++) inv[i][r] = 1.f / l_r[i][r];
    #pragma unroll
    for (int i = 0; i < 2; i++)
        #pragma unroll
        for (int od = 0; od < 4; od++)
            #pragma unroll
            for (int r = 0; r < 4; r++)
                Pw[(i * 16 + lq * 4 + r) * KR + od * 16 + col] = (bf16_t)(Oacc[i][od][r] * inv[i][r]);
    __syncthreads();
    #pragma unroll
    for (int it = 0; it < 4; it++) {
        int idx = lane + it * 64;
        int row = idx >> 3, g = idx & 7;
        int gs = bi * BLK + qr0 + row;
        *(bf16x8*)(o + ((size_t)(b * SEQ + gs)) * WIDTH + h * DH + g * 8) =
            *(const bf16x8*)(Pw + row * KR + g * 8);
    }
}

extern "C" void kernel_launch(void* const* d_in, const int* in_sizes, int n_in,
                              void* d_out, int out_size, void* d_ws, size_t ws_size,
                              hipStream_t stream) {
    const float* x     = (const float*)d_in[0];
    const float* f     = (const float*)d_in[1];
    const float* delim = (const float*)d_in[2];
    const float* ln1_s = (const float*)d_in[3];
    const float* ln1_b = (const float*)d_in[4];
    const float* w_qkv = (const float*)d_in[5];
    const float* b_qkv = (const float*)d_in[6];
    const float* w_out = (const float*)d_in[7];
    const float* b_out = (const float*)d_in[8];
    const float* ln2_s = (const float*)d_in[9];
    const float* ln2_b = (const float*)d_in[10];
    const float* w_fc  = (const float*)d_in[11];
    const float* b_fc  = (const float*)d_in[12];
    const float* w_pr  = (const float*)d_in[13];
    const float* b_pr  = (const float*)d_in[14];
    const float* w_hd  = (const float*)d_in[15];
    float* out = (float*)d_out;

    // workspace layout (~82 MB total):
    // h fp32 (14.35) | big_bf (28.7; qkv uses 1536-wide, attn-out o_bf aliases the tail)
    // | stats (56 KB + 64 KB slack) | bf16 weights (38.8)
    char* base = (char*)d_ws;
    float*  h      = (float*)base;    base += (size_t)MROWS * WIDTH * 4;
    bf16_t* big_bf = (bf16_t*)base;   base += (size_t)MROWS * 2048 * 2;
    bf16_t* o_bf   = big_bf + (size_t)MROWS * 1536;   // tail alias: MROWS*512 bf16
    float2* stats  = (float2*)base;   base += (size_t)MROWS * 8 + 65536;
    bf16_t* wi_bf  = (bf16_t*)base;   base += (size_t)LAYERS * 1536 * 512 * 2;
    bf16_t* wo_bf  = (bf16_t*)base;   base += (size_t)LAYERS * 512 * 512 * 2;
    bf16_t* wfc_bf = (bf16_t*)base;   base += (size_t)LAYERS * 2048 * 512 * 2;
    bf16_t* wpr_bf = (bf16_t*)base;   base += (size_t)LAYERS * 512 * 2048 * 2;
    bf16_t* wh_bf  = (bf16_t*)base;   base += (size_t)VOCAB * 512 * 2;

    // hoisted weight casts (once per launch)
    cast_kernel<<<LAYERS * 1536 * 512 / 1024, 256, 0, stream>>>(w_qkv, wi_bf, LAYERS * 1536 * 512 / 4);
    cast_kernel<<<LAYERS * 512 * 512 / 1024, 256, 0, stream>>>(w_out, wo_bf, LAYERS * 512 * 512 / 4);
    cast_kernel<<<LAYERS * 2048 * 512 / 1024, 256, 0, stream>>>(w_fc, wfc_bf, LAYERS * 2048 * 512 / 4);
    cast_kernel<<<LAYERS * 512 * 2048 / 1024, 256, 0, stream>>>(w_pr, wpr_bf, LAYERS * 512 * 2048 / 4);
    cast_kernel<<<VOCAB * 512 / 1024, 256, 0, stream>>>(w_hd, wh_bf, VOCAB * 512 / 4);

    embed_kernel<<<(BATCH * SEQ * WIDTH) / 256, 256, 0, stream>>>(x, f, delim, h);

    const int MT = (MROWS + TM - 1) / TM;   // 55
    for (int l = 0; l < LAYERS; l++) {
        ln_stats_kernel<<<MROWS / 4, 256, 0, stream>>>(h, stats);
        gemm_f<1, 3, 128><<<dim3(1536 / 128, MT), 256, 0, stream>>>(
            nullptr, h, stats, ln1_s + l * WIDTH, ln1_b + l * WIDTH,
            wi_bf + (size_t)l * 1536 * 512, b_qkv + (size_t)l * 1536,
            nullptr, big_bf, MROWS, 1536, 512);
        attn_mfma<<<dim3(NFR, HEADS, BATCH), 256, 0, stream>>>(big_bf, o_bf);
        gemm_f<0, 2, 64><<<dim3(512 / 64, MT), 256, 0, stream>>>(
            o_bf, nullptr, nullptr, nullptr, nullptr,
            wo_bf + (size_t)l * 512 * 512, b_out + (size_t)l * 512,
            h, nullptr, MROWS, 512, 512);
        ln_stats_kernel<<<MROWS / 4, 256, 0, stream>>>(h, stats);
        gemm_f<1, 1, 128><<<dim3(2048 / 128, MT), 256, 0, stream>>>(
            nullptr, h, stats, ln2_s + l * WIDTH, ln2_b + l * WIDTH,
            wfc_bf + (size_t)l * 2048 * 512, b_fc + (size_t)l * 2048,
            nullptr, big_bf, MROWS, 2048, 512);
        gemm_f<0, 2, 64><<<dim3(512 / 64, MT), 256, 0, stream>>>(
            big_bf, nullptr, nullptr, nullptr, nullptr,
            wpr_bf + (size_t)l * 512 * 2048, b_pr + (size_t)l * 512,
            h, nullptr, MROWS, 512, 2048);
    }

    gemm_f<2, 0, 64><<<dim3(VOCAB / 64, OUTROWS / TM), 256, 0, stream>>>(
        nullptr, h, nullptr, nullptr, nullptr,
        wh_bf, nullptr, out, nullptr, OUTROWS, VOCAB, 512);
}